// Round 1
// baseline (1880.678 us; speedup 1.0000x reference)
//
#include <hip/hip_runtime.h>
#include <math.h>

static constexpr int NN = 50000;
static constexpr int NE = 800000;

__device__ __forceinline__ float leakyf(float x, float s) { return x > 0.f ? x : s * x; }

// ============================ CSR build ============================
__global__ void k_count(const int* __restrict__ dst, int* __restrict__ cnt, int n) {
    int e = blockIdx.x * 256 + threadIdx.x;
    if (e < n) atomicAdd(&cnt[dst[e]], 1);
}

__global__ void k_scan1(const int* __restrict__ cnt, int* __restrict__ rp,
                        int* __restrict__ partials, int n) {
    __shared__ int sm[256];
    int tid = threadIdx.x;
    int i = blockIdx.x * 256 + tid;
    int v = (i < n) ? cnt[i] : 0;
    int x = v;
    sm[tid] = x;
    __syncthreads();
    for (int off = 1; off < 256; off <<= 1) {
        int t = (tid >= off) ? sm[tid - off] : 0;
        __syncthreads();
        x += t;
        sm[tid] = x;
        __syncthreads();
    }
    if (i < n) rp[i] = x - v;            // exclusive within block
    if (tid == 255) partials[blockIdx.x] = x;  // block total
}

__global__ void k_scan2(const int* __restrict__ partials, int* __restrict__ poffs, int nb) {
    __shared__ int sm[256];
    int tid = threadIdx.x;
    int v = (tid < nb) ? partials[tid] : 0;
    int x = v;
    sm[tid] = x;
    __syncthreads();
    for (int off = 1; off < 256; off <<= 1) {
        int t = (tid >= off) ? sm[tid - off] : 0;
        __syncthreads();
        x += t;
        sm[tid] = x;
        __syncthreads();
    }
    if (tid < nb) poffs[tid] = x - v;
}

__global__ void k_scan3(int* __restrict__ rp, const int* __restrict__ poffs,
                        int* __restrict__ woff, int n, int total) {
    int i = blockIdx.x * 256 + threadIdx.x;
    if (i < n) {
        int v = rp[i] + poffs[blockIdx.x];
        rp[i] = v;
        woff[i] = v;
    }
    if (i == 0) rp[n] = total;
}

__global__ void k_scatter(const int* __restrict__ srcA, const int* __restrict__ dstA,
                          const float* __restrict__ ea, int* __restrict__ woff,
                          int* __restrict__ csr_src, float* __restrict__ csr_ea, int n) {
    int e = blockIdx.x * 256 + threadIdx.x;
    if (e < n) {
        int d = dstA[e];
        int pos = atomicAdd(&woff[d], 1);
        csr_src[pos] = srcA[e];
        csr_ea[pos] = ea[e];
    }
}

// ============================ GEMM ============================
// C[M,Nc] = A[M,K] @ W[Nc,K]^T + bias[Nc]   (A, W row-major; K%16==0, Nc%64==0)
__global__ __launch_bounds__(256) void k_gemm_nt(const float* __restrict__ A,
                                                 const float* __restrict__ W,
                                                 const float* __restrict__ bias,
                                                 float* __restrict__ C,
                                                 int M, int Nc, int K) {
    __shared__ float As[16][68];   // [k][m], padded
    __shared__ float Bs[16][68];   // [k][n], padded
    const int tid  = threadIdx.x;
    const int bm   = blockIdx.x * 64;
    const int bn   = blockIdx.y * 64;
    const int lrow = tid >> 2;          // 0..63
    const int lcol = (tid & 3) * 4;     // 0,4,8,12
    const int tx   = tid & 15;          // col group
    const int ty   = tid >> 4;          // row group
    const int arow = bm + lrow;
    const bool aok = arow < M;

    float acc[4][4] = {};

    for (int k0 = 0; k0 < K; k0 += 16) {
        float4 av = make_float4(0.f, 0.f, 0.f, 0.f);
        if (aok) av = *(const float4*)&A[(size_t)arow * K + k0 + lcol];
        float4 bv = *(const float4*)&W[(size_t)(bn + lrow) * K + k0 + lcol];
        As[lcol + 0][lrow] = av.x; As[lcol + 1][lrow] = av.y;
        As[lcol + 2][lrow] = av.z; As[lcol + 3][lrow] = av.w;
        Bs[lcol + 0][lrow] = bv.x; Bs[lcol + 1][lrow] = bv.y;
        Bs[lcol + 2][lrow] = bv.z; Bs[lcol + 3][lrow] = bv.w;
        __syncthreads();
#pragma unroll
        for (int kk = 0; kk < 16; ++kk) {
            float4 a4 = *(const float4*)&As[kk][ty * 4];
            float4 b4 = *(const float4*)&Bs[kk][tx * 4];
            float a[4] = {a4.x, a4.y, a4.z, a4.w};
            float b[4] = {b4.x, b4.y, b4.z, b4.w};
#pragma unroll
            for (int i = 0; i < 4; ++i)
#pragma unroll
                for (int j = 0; j < 4; ++j)
                    acc[i][j] += a[i] * b[j];
        }
        __syncthreads();
    }

#pragma unroll
    for (int i = 0; i < 4; ++i) {
        int r = bm + ty * 4 + i;
        if (r < M) {
#pragma unroll
            for (int j = 0; j < 4; ++j) {
                int c = bn + tx * 4 + j;
                C[(size_t)r * Nc + c] = acc[i][j] + bias[c];
            }
        }
    }
}

// ============================ Fused GAT edge + softmax + LN + residual ============================
// One wave per destination node; online (flash) softmax over its incoming edges.
// HC = heads*64 channels; lane owns VPL = HC/64 contiguous channels.
template <int HC>
__global__ __launch_bounds__(256) void k_gat_edge(
    const float* __restrict__ xl, const float* __restrict__ xr,
    const int* __restrict__ rp, const int* __restrict__ csr_src,
    const float* __restrict__ csr_ea,
    const float* __restrict__ We, const float* __restrict__ att,
    const float* __restrict__ bias, const float* __restrict__ gamma,
    const float* __restrict__ beta, const float* __restrict__ res,
    float* __restrict__ out, int n) {
    constexpr int VPL = HC / 64;          // values per lane
    constexpr int LPH = 64 * 64 / HC;     // lanes per head (head = 64 channels)
    const int lane = threadIdx.x & 63;
    const int node = blockIdx.x * 4 + (threadIdx.x >> 6);
    if (node >= n) return;
    const int vb = lane * VPL;

    float xrd[VPL], wev[VPL], attv[VPL];
    if constexpr (VPL == 4) {
        float4 t = *(const float4*)&xr[(size_t)node * HC + vb];
        xrd[0] = t.x; xrd[1] = t.y; xrd[2] = t.z; xrd[3] = t.w;
    } else {
        xrd[0] = xr[(size_t)node * HC + vb];
    }
#pragma unroll
    for (int i = 0; i < VPL; ++i) {
        wev[i]  = We[vb + i];
        attv[i] = att[vb + i];
    }

    float m = -INFINITY, denom = 0.f;
    float acc[VPL] = {};
    const int s = rp[node], e = rp[node + 1];

    for (int p = s; p < e; ++p) {
        int src  = csr_src[p];
        float ea = csr_ea[p];
        float xls[VPL];
        if constexpr (VPL == 4) {
            float4 t = *(const float4*)&xl[(size_t)src * HC + vb];
            xls[0] = t.x; xls[1] = t.y; xls[2] = t.z; xls[3] = t.w;
        } else {
            xls[0] = xl[(size_t)src * HC + vb];
        }
        float part = 0.f;
#pragma unroll
        for (int i = 0; i < VPL; ++i) {
            float z = xls[i] + xrd[i] + ea * wev[i];
            z = leakyf(z, 0.2f);
            part += attv[i] * z;
        }
#pragma unroll
        for (int off = 1; off < LPH; off <<= 1) part += __shfl_xor(part, off);
        // online softmax update (per head; uniform within 16/64-lane group)
        float mn = fmaxf(m, part);
        float sc = __expf(m - mn);      // 0 when m == -inf
        float pw = __expf(part - mn);
        denom = denom * sc + pw;
#pragma unroll
        for (int i = 0; i < VPL; ++i) acc[i] = acc[i] * sc + pw * xls[i];
        m = mn;
    }

    float o[VPL];
    float inv = (e > s) ? 1.f / denom : 0.f;
#pragma unroll
    for (int i = 0; i < VPL; ++i) o[i] = acc[i] * inv + bias[vb + i];

    // LayerNorm over HC channels (wave-wide reduction)
    float sum = 0.f;
#pragma unroll
    for (int i = 0; i < VPL; ++i) sum += o[i];
#pragma unroll
    for (int off = 1; off < 64; off <<= 1) sum += __shfl_xor(sum, off);
    float mu = sum * (1.f / HC);
    float sq = 0.f;
#pragma unroll
    for (int i = 0; i < VPL; ++i) { float d = o[i] - mu; sq += d * d; }
#pragma unroll
    for (int off = 1; off < 64; off <<= 1) sq += __shfl_xor(sq, off);
    float rstd = rsqrtf(sq * (1.f / HC) + 1e-5f);

#pragma unroll
    for (int i = 0; i < VPL; ++i) {
        float y = (o[i] - mu) * rstd * gamma[vb + i] + beta[vb + i];
        y = leakyf(y, 0.01f);
        out[(size_t)node * HC + vb + i] = y + res[(size_t)node * HC + vb + i];
    }
}

// ============================ launch ============================
extern "C" void kernel_launch(void* const* d_in, const int* in_sizes, int n_in,
                              void* d_out, int out_size, void* d_ws, size_t ws_size,
                              hipStream_t stream) {
    const int*   ei  = (const int*)d_in[0];          // [2,E]
    const float* ea  = (const float*)d_in[1];        // [E,1]
    const float* x   = (const float*)d_in[2];        // [N,768]
    const float* Wl0 = (const float*)d_in[3],  *bl0 = (const float*)d_in[4];
    const float* Wr0 = (const float*)d_in[5],  *br0 = (const float*)d_in[6];
    const float* We0 = (const float*)d_in[7],  *att0= (const float*)d_in[8];
    const float* b0  = (const float*)d_in[9],  *g0  = (const float*)d_in[10], *be0 = (const float*)d_in[11];
    const float* Wl1 = (const float*)d_in[12], *bl1 = (const float*)d_in[13];
    const float* Wr1 = (const float*)d_in[14], *br1 = (const float*)d_in[15];
    const float* We1 = (const float*)d_in[16], *att1= (const float*)d_in[17];
    const float* b1  = (const float*)d_in[18], *g1  = (const float*)d_in[19], *be1 = (const float*)d_in[20];
    const float* Wl2 = (const float*)d_in[21], *bl2 = (const float*)d_in[22];
    const float* Wr2 = (const float*)d_in[23], *br2 = (const float*)d_in[24];
    const float* We2 = (const float*)d_in[25], *att2= (const float*)d_in[26];
    const float* b2  = (const float*)d_in[27], *g2  = (const float*)d_in[28], *be2 = (const float*)d_in[29];
    const float* Rw0 = (const float*)d_in[30], *Rb0 = (const float*)d_in[31];
    const float* Rw2 = (const float*)d_in[32], *Rb2 = (const float*)d_in[33];

    const int* srcA = ei;
    const int* dstA = ei + NE;

    float* ws = (float*)d_ws;
    size_t o = 0;
    auto allocf = [&](size_t nf) { float* p = ws + o; o += nf; return p; };
    float* B0 = allocf((size_t)NN * 256);   // xl
    float* B1 = allocf((size_t)NN * 256);   // xr
    float* B2 = allocf((size_t)NN * 256);   // residual proj
    float* B3 = allocf((size_t)NN * 256);   // h  (layer0 out)
    float* B4 = allocf((size_t)NN * 256);   // h1 (layer1 out)
    int* cnt      = (int*)(ws + o); o += NN;
    int* rp       = (int*)(ws + o); o += NN + 4;
    int* woff     = (int*)(ws + o); o += NN;
    int* partials = (int*)(ws + o); o += 256;
    int* poffs    = (int*)(ws + o); o += 256;
    int* csr_src  = (int*)(ws + o); o += NE;
    float* csr_ea = (float*)(ws + o); o += NE;

    float* outp = (float*)d_out;

    const int NB_N = (NN + 255) / 256;   // 196
    const int NB_E = (NE + 255) / 256;

    // ---- CSR build ----
    hipMemsetAsync(cnt, 0, (size_t)NN * sizeof(int), stream);
    k_count<<<NB_E, 256, 0, stream>>>(dstA, cnt, NE);
    k_scan1<<<NB_N, 256, 0, stream>>>(cnt, rp, partials, NN);
    k_scan2<<<1, 256, 0, stream>>>(partials, poffs, NB_N);
    k_scan3<<<NB_N, 256, 0, stream>>>(rp, poffs, woff, NN, NE);
    k_scatter<<<NB_E, 256, 0, stream>>>(srcA, dstA, ea, woff, csr_src, csr_ea, NE);

    auto gemm = [&](const float* A, const float* W, const float* bias, float* C,
                    int M, int Nc, int K) {
        dim3 g((M + 63) / 64, Nc / 64);
        k_gemm_nt<<<g, 256, 0, stream>>>(A, W, bias, C, M, Nc, K);
    };

    const int EG = (NN + 3) / 4;   // edge-kernel grid (4 nodes/block)

    // ---- layer 0 (768 -> 4x64 concat = 256) ----
    gemm(x, Wl0, bl0, B0, NN, 256, 768);
    gemm(x, Wr0, br0, B1, NN, 256, 768);
    gemm(x, Rw0, Rb0, B2, NN, 256, 768);
    k_gat_edge<256><<<EG, 256, 0, stream>>>(B0, B1, rp, csr_src, csr_ea,
                                            We0, att0, b0, g0, be0, B2, B3, NN);

    // ---- layer 1 (256 -> 4x64 concat = 256), identity residual ----
    gemm(B3, Wl1, bl1, B0, NN, 256, 256);
    gemm(B3, Wr1, br1, B1, NN, 256, 256);
    k_gat_edge<256><<<EG, 256, 0, stream>>>(B0, B1, rp, csr_src, csr_ea,
                                            We1, att1, b1, g1, be1, B3, B4, NN);

    // ---- layer 2 (256 -> 1x64 mean = 64) ----
    gemm(B4, Wl2, bl2, B0, NN, 64, 256);
    gemm(B4, Wr2, br2, B1, NN, 64, 256);
    gemm(B4, Rw2, Rb2, B2, NN, 64, 256);
    k_gat_edge<64><<<EG, 256, 0, stream>>>(B0, B1, rp, csr_src, csr_ea,
                                           We2, att2, b2, g2, be2, B2, outp, NN);
}

// Round 3
// 1062.730 us; speedup vs baseline: 1.7697x; 1.7697x over previous
//
#include <hip/hip_runtime.h>
#include <math.h>

static constexpr int NN = 50000;
static constexpr int NE = 800000;
static constexpr int MPAD = 50048;   // 391 * 128

typedef __attribute__((ext_vector_type(8))) __bf16 bf16x8;
typedef __attribute__((ext_vector_type(4))) float f32x4;
typedef __bf16 bf16_t;

__device__ __forceinline__ float leakyf(float x, float s) { return x > 0.f ? x : s * x; }

// ============================ CSR build ============================
__global__ void k_count(const int* __restrict__ dst, int* __restrict__ cnt, int n) {
    int e = blockIdx.x * 256 + threadIdx.x;
    if (e < n) atomicAdd(&cnt[dst[e]], 1);
}

__global__ void k_scan1(const int* __restrict__ cnt, int* __restrict__ rp,
                        int* __restrict__ partials, int n) {
    __shared__ int sm[256];
    int tid = threadIdx.x;
    int i = blockIdx.x * 256 + tid;
    int v = (i < n) ? cnt[i] : 0;
    int x = v;
    sm[tid] = x;
    __syncthreads();
    for (int off = 1; off < 256; off <<= 1) {
        int t = (tid >= off) ? sm[tid - off] : 0;
        __syncthreads();
        x += t;
        sm[tid] = x;
        __syncthreads();
    }
    if (i < n) rp[i] = x - v;
    if (tid == 255) partials[blockIdx.x] = x;
}

__global__ void k_scan2(const int* __restrict__ partials, int* __restrict__ poffs, int nb) {
    __shared__ int sm[256];
    int tid = threadIdx.x;
    int v = (tid < nb) ? partials[tid] : 0;
    int x = v;
    sm[tid] = x;
    __syncthreads();
    for (int off = 1; off < 256; off <<= 1) {
        int t = (tid >= off) ? sm[tid - off] : 0;
        __syncthreads();
        x += t;
        sm[tid] = x;
        __syncthreads();
    }
    if (tid < nb) poffs[tid] = x - v;
}

__global__ void k_scan3(int* __restrict__ rp, const int* __restrict__ poffs,
                        int* __restrict__ woff, int n, int total) {
    int i = blockIdx.x * 256 + threadIdx.x;
    if (i < n) {
        int v = rp[i] + poffs[blockIdx.x];
        rp[i] = v;
        woff[i] = v;
    }
    if (i == 0) rp[n] = total;
}

__global__ void k_scatter(const int* __restrict__ srcA, const int* __restrict__ dstA,
                          const float* __restrict__ ea, int* __restrict__ woff,
                          int* __restrict__ csr_src, float* __restrict__ csr_ea, int n) {
    int e = blockIdx.x * 256 + threadIdx.x;
    if (e < n) {
        int d = dstA[e];
        int pos = atomicAdd(&woff[d], 1);
        csr_src[pos] = srcA[e];
        csr_ea[pos] = ea[e];
    }
}

// ============================ f32 -> bf16 conversion ============================
__global__ void k_f2b(const float* __restrict__ s, bf16_t* __restrict__ d, int n) {
    for (int i = (blockIdx.x * 256 + threadIdx.x) * 8; i < n; i += gridDim.x * 256 * 8) {
        float4 a = *(const float4*)&s[i];
        float4 b = *(const float4*)&s[i + 4];
        bf16x8 o;
        o[0] = (__bf16)a.x; o[1] = (__bf16)a.y; o[2] = (__bf16)a.z; o[3] = (__bf16)a.w;
        o[4] = (__bf16)b.x; o[5] = (__bf16)b.y; o[6] = (__bf16)b.z; o[7] = (__bf16)b.w;
        *(bf16x8*)&d[i] = o;
    }
}

// 8 weight matrices in one launch (blockIdx.y selects matrix)
__global__ void k_f2bw(const float* s0, bf16_t* d0, int n0,
                       const float* s1, bf16_t* d1, int n1,
                       const float* s2, bf16_t* d2, int n2,
                       const float* s3, bf16_t* d3, int n3,
                       const float* s4, bf16_t* d4, int n4,
                       const float* s5, bf16_t* d5, int n5,
                       const float* s6, bf16_t* d6, int n6,
                       const float* s7, bf16_t* d7, int n7) {
    const float* s; bf16_t* d; int n;
    switch (blockIdx.y) {
        case 0: s = s0; d = d0; n = n0; break;
        case 1: s = s1; d = d1; n = n1; break;
        case 2: s = s2; d = d2; n = n2; break;
        case 3: s = s3; d = d3; n = n3; break;
        case 4: s = s4; d = d4; n = n4; break;
        case 5: s = s5; d = d5; n = n5; break;
        case 6: s = s6; d = d6; n = n6; break;
        default: s = s7; d = d7; n = n7; break;
    }
    for (int i = (blockIdx.x * 256 + threadIdx.x) * 8; i < n; i += gridDim.x * 256 * 8) {
        float4 a = *(const float4*)&s[i];
        float4 b = *(const float4*)&s[i + 4];
        bf16x8 o;
        o[0] = (__bf16)a.x; o[1] = (__bf16)a.y; o[2] = (__bf16)a.z; o[3] = (__bf16)a.w;
        o[4] = (__bf16)b.x; o[5] = (__bf16)b.y; o[6] = (__bf16)b.z; o[7] = (__bf16)b.w;
        *(bf16x8*)&d[i] = o;
    }
}

// ============================ MFMA GEMM ============================
// C[M,Nc] = A[Mpad,K]_bf16 @ W[Nc,K]_bf16^T + bias. BM=128, BK=32.
// 4 waves in 2x2; wave tile 64 x (BN/2). K%32==0, Nc%BN==0, A padded to 128-row multiple.
template <int BN>
__global__ __launch_bounds__(256) void k_gemm_mfma(
    const bf16_t* __restrict__ A, const bf16_t* __restrict__ W,
    const float* __restrict__ bias, float* __restrict__ C,
    int M, int Nc, int K) {
    constexpr int BM = 128;
    constexpr int FRN = BN / 32;       // B fragments per wave
    constexpr int WN = BN / 2;         // wave cols
    constexpr int BCHW = BN / 64;      // B staging chunks per wave

    __shared__ __align__(16) bf16_t As[BM * 32];
    __shared__ __align__(16) bf16_t Bs[BN * 32];

    const int tid = threadIdx.x;
    const int wid = tid >> 6;
    const int lane = tid & 63;
    const int wr = wid >> 1, wc = wid & 1;
    const int bm = blockIdx.x * BM;
    const int bn = blockIdx.y * BN;

    // staging lane geometry: 4 lanes per row (8 bf16 = 16B each)
    const int srow = lane >> 2;
    const int scol = (lane & 3) * 8;

    f32x4 acc[4][FRN];
#pragma unroll
    for (int m = 0; m < 4; ++m)
#pragma unroll
        for (int n = 0; n < FRN; ++n) acc[m][n] = (f32x4){0.f, 0.f, 0.f, 0.f};

    const bf16_t* ag[2];
#pragma unroll
    for (int j = 0; j < 2; ++j)
        ag[j] = A + (size_t)(bm + (wid * 2 + j) * 16 + srow) * K + scol;
    const bf16_t* bg[BCHW];
#pragma unroll
    for (int j = 0; j < BCHW; ++j)
        bg[j] = W + (size_t)(bn + (wid * BCHW + j) * 16 + srow) * K + scol;

    for (int k0 = 0; k0 < K; k0 += 32) {
#pragma unroll
        for (int j = 0; j < 2; ++j) {
            __builtin_amdgcn_global_load_lds(
                (const __attribute__((address_space(1))) void*)(ag[j] + k0),
                (__attribute__((address_space(3))) void*)(As + (wid * 2 + j) * 512),
                16, 0, 0);
        }
#pragma unroll
        for (int j = 0; j < BCHW; ++j) {
            __builtin_amdgcn_global_load_lds(
                (const __attribute__((address_space(1))) void*)(bg[j] + k0),
                (__attribute__((address_space(3))) void*)(Bs + (wid * BCHW + j) * 512),
                16, 0, 0);
        }
        __syncthreads();

        bf16x8 bfr[FRN];
#pragma unroll
        for (int n = 0; n < FRN; ++n)
            bfr[n] = *(const bf16x8*)&Bs[(wc * WN + n * 16 + (lane & 15)) * 32 + (lane >> 4) * 8];
        bf16x8 afr[4];
#pragma unroll
        for (int m = 0; m < 4; ++m)
            afr[m] = *(const bf16x8*)&As[(wr * 64 + m * 16 + (lane & 15)) * 32 + (lane >> 4) * 8];
#pragma unroll
        for (int m = 0; m < 4; ++m)
#pragma unroll
            for (int n = 0; n < FRN; ++n)
                acc[m][n] = __builtin_amdgcn_mfma_f32_16x16x32_bf16(afr[m], bfr[n], acc[m][n], 0, 0, 0);
        __syncthreads();
    }

    const int cr = (lane >> 4) * 4;
    const int cc = lane & 15;
#pragma unroll
    for (int m = 0; m < 4; ++m) {
        int row0 = bm + wr * 64 + m * 16 + cr;
#pragma unroll
        for (int n = 0; n < FRN; ++n) {
            int col = bn + wc * WN + n * 16 + cc;
            float bv = bias[col];
#pragma unroll
            for (int j = 0; j < 4; ++j) {
                int r = row0 + j;
                if (r < M) C[(size_t)r * Nc + col] = acc[m][n][j] + bv;
            }
        }
    }
}

// ============================ Fused GAT edge + softmax + LN + residual ============================
template <int HC>
__global__ __launch_bounds__(256) void k_gat_edge(
    const float* __restrict__ xl, const float* __restrict__ xr,
    const int* __restrict__ rp, const int* __restrict__ csr_src,
    const float* __restrict__ csr_ea,
    const float* __restrict__ We, const float* __restrict__ att,
    const float* __restrict__ bias, const float* __restrict__ gamma,
    const float* __restrict__ beta, const float* __restrict__ res,
    float* __restrict__ out, int n) {
    constexpr int VPL = HC / 64;
    constexpr int LPH = 64 * 64 / HC;
    const int lane = threadIdx.x & 63;
    const int node = blockIdx.x * 4 + (threadIdx.x >> 6);
    if (node >= n) return;
    const int vb = lane * VPL;

    float xrd[VPL], wev[VPL], attv[VPL];
    if constexpr (VPL == 4) {
        float4 t = *(const float4*)&xr[(size_t)node * HC + vb];
        xrd[0] = t.x; xrd[1] = t.y; xrd[2] = t.z; xrd[3] = t.w;
    } else {
        xrd[0] = xr[(size_t)node * HC + vb];
    }
#pragma unroll
    for (int i = 0; i < VPL; ++i) {
        wev[i]  = We[vb + i];
        attv[i] = att[vb + i];
    }

    float m = -INFINITY, denom = 0.f;
    float acc[VPL] = {};
    const int s = rp[node], e = rp[node + 1];

    for (int p = s; p < e; ++p) {
        int src  = csr_src[p];
        float ea = csr_ea[p];
        float xls[VPL];
        if constexpr (VPL == 4) {
            float4 t = *(const float4*)&xl[(size_t)src * HC + vb];
            xls[0] = t.x; xls[1] = t.y; xls[2] = t.z; xls[3] = t.w;
        } else {
            xls[0] = xl[(size_t)src * HC + vb];
        }
        float part = 0.f;
#pragma unroll
        for (int i = 0; i < VPL; ++i) {
            float z = xls[i] + xrd[i] + ea * wev[i];
            z = leakyf(z, 0.2f);
            part += attv[i] * z;
        }
#pragma unroll
        for (int off = 1; off < LPH; off <<= 1) part += __shfl_xor(part, off);
        float mn = fmaxf(m, part);
        float sc = __expf(m - mn);
        float pw = __expf(part - mn);
        denom = denom * sc + pw;
#pragma unroll
        for (int i = 0; i < VPL; ++i) acc[i] = acc[i] * sc + pw * xls[i];
        m = mn;
    }

    float o[VPL];
    float inv = (e > s) ? 1.f / denom : 0.f;
#pragma unroll
    for (int i = 0; i < VPL; ++i) o[i] = acc[i] * inv + bias[vb + i];

    float sum = 0.f;
#pragma unroll
    for (int i = 0; i < VPL; ++i) sum += o[i];
#pragma unroll
    for (int off = 1; off < 64; off <<= 1) sum += __shfl_xor(sum, off);
    float mu = sum * (1.f / HC);
    float sq = 0.f;
#pragma unroll
    for (int i = 0; i < VPL; ++i) { float d = o[i] - mu; sq += d * d; }
#pragma unroll
    for (int off = 1; off < 64; off <<= 1) sq += __shfl_xor(sq, off);
    float rstd = rsqrtf(sq * (1.f / HC) + 1e-5f);

#pragma unroll
    for (int i = 0; i < VPL; ++i) {
        float y = (o[i] - mu) * rstd * gamma[vb + i] + beta[vb + i];
        y = leakyf(y, 0.01f);
        out[(size_t)node * HC + vb + i] = y + res[(size_t)node * HC + vb + i];
    }
}

// ============================ launch ============================
extern "C" void kernel_launch(void* const* d_in, const int* in_sizes, int n_in,
                              void* d_out, int out_size, void* d_ws, size_t ws_size,
                              hipStream_t stream) {
    const int*   ei  = (const int*)d_in[0];
    const float* ea  = (const float*)d_in[1];
    const float* x   = (const float*)d_in[2];
    const float* Wl0 = (const float*)d_in[3],  *bl0 = (const float*)d_in[4];
    const float* Wr0 = (const float*)d_in[5],  *br0 = (const float*)d_in[6];
    const float* We0 = (const float*)d_in[7],  *att0= (const float*)d_in[8];
    const float* b0  = (const float*)d_in[9],  *g0  = (const float*)d_in[10], *be0 = (const float*)d_in[11];
    const float* Wl1 = (const float*)d_in[12], *bl1 = (const float*)d_in[13];
    const float* Wr1 = (const float*)d_in[14], *br1 = (const float*)d_in[15];
    const float* We1 = (const float*)d_in[16], *att1= (const float*)d_in[17];
    const float* b1  = (const float*)d_in[18], *g1  = (const float*)d_in[19], *be1 = (const float*)d_in[20];
    const float* Wl2 = (const float*)d_in[21], *bl2 = (const float*)d_in[22];
    const float* Wr2 = (const float*)d_in[23], *br2 = (const float*)d_in[24];
    const float* We2 = (const float*)d_in[25], *att2= (const float*)d_in[26];
    const float* b2  = (const float*)d_in[27], *g2  = (const float*)d_in[28], *be2 = (const float*)d_in[29];
    const float* Rw0 = (const float*)d_in[30], *Rb0 = (const float*)d_in[31];
    const float* Rw2 = (const float*)d_in[32], *Rb2 = (const float*)d_in[33];

    const int* srcA = ei;
    const int* dstA = ei + NE;

    float* ws = (float*)d_ws;
    size_t o = 0;
    auto allocf = [&](size_t nf) { float* p = ws + o; o += nf; return p; };
    float* B0 = allocf((size_t)MPAD * 256);   // xl
    float* B1 = allocf((size_t)MPAD * 256);   // xr
    float* B2 = allocf((size_t)MPAD * 256);   // residual proj (L0/L2) / h1 (L1 out)
    float* B3 = allocf((size_t)MPAD * 256);   // h (L0 out), then L2 residual buffer
    bf16_t* xb = (bf16_t*)allocf((size_t)MPAD * 768 / 2);   // bf16 x; later reused as bf16 h/h1
    bf16_t* hb = xb;                                        // alias: xb dead after layer-0 GEMMs
    // weight pool: needs 3*196608 + 2*65536 + 3*16384 = 770048 bf16 -> allocate 786432
    bf16_t* wb = (bf16_t*)allocf(786432 / 2);
    int* cnt      = (int*)(ws + o); o += NN;
    int* rp       = (int*)(ws + o); o += NN + 4;
    int* woff     = (int*)(ws + o); o += NN;
    int* partials = (int*)(ws + o); o += 256;
    int* poffs    = (int*)(ws + o); o += 256;
    int* csr_src  = (int*)(ws + o); o += NE;
    float* csr_ea = (float*)(ws + o); o += NE;

    bf16_t* Wl0b = wb;                   // 256*768
    bf16_t* Wr0b = Wl0b + 196608;
    bf16_t* Rw0b = Wr0b + 196608;
    bf16_t* Wl1b = Rw0b + 196608;        // 256*256
    bf16_t* Wr1b = Wl1b + 65536;
    bf16_t* Wl2b = Wr1b + 65536;         // 64*256
    bf16_t* Wr2b = Wl2b + 16384;
    bf16_t* Rw2b = Wr2b + 16384;

    float* outp = (float*)d_out;

    const int NB_N = (NN + 255) / 256;
    const int NB_E = (NE + 255) / 256;

    // ---- CSR build ----
    hipMemsetAsync(cnt, 0, (size_t)NN * sizeof(int), stream);
    k_count<<<NB_E, 256, 0, stream>>>(dstA, cnt, NE);
    k_scan1<<<NB_N, 256, 0, stream>>>(cnt, rp, partials, NN);
    k_scan2<<<1, 256, 0, stream>>>(partials, poffs, NB_N);
    k_scan3<<<NB_N, 256, 0, stream>>>(rp, poffs, woff, NN, NE);
    k_scatter<<<NB_E, 256, 0, stream>>>(srcA, dstA, ea, woff, csr_src, csr_ea, NE);

    // ---- dtype conversions (x + all weights) ----
    k_f2b<<<2048, 256, 0, stream>>>(x, xb, NN * 768);
    {
        dim3 g(96, 8);
        k_f2bw<<<g, 256, 0, stream>>>(Wl0, Wl0b, 196608, Wr0, Wr0b, 196608,
                                      Rw0, Rw0b, 196608, Wl1, Wl1b, 65536,
                                      Wr1, Wr1b, 65536,  Wl2, Wl2b, 16384,
                                      Wr2, Wr2b, 16384,  Rw2, Rw2b, 16384);
    }

    const int MB = MPAD / 128;            // 391
    const int EG = (NN + 3) / 4;

    // ---- layer 0 (768 -> 4x64 concat = 256) ----
    {
        dim3 g(MB, 2);
        k_gemm_mfma<128><<<g, 256, 0, stream>>>(xb, Wl0b, bl0, B0, NN, 256, 768);
        k_gemm_mfma<128><<<g, 256, 0, stream>>>(xb, Wr0b, br0, B1, NN, 256, 768);
        k_gemm_mfma<128><<<g, 256, 0, stream>>>(xb, Rw0b, Rb0, B2, NN, 256, 768);
    }
    k_gat_edge<256><<<EG, 256, 0, stream>>>(B0, B1, rp, csr_src, csr_ea,
                                            We0, att0, b0, g0, be0, B2, B3, NN);

    // ---- layer 1 (256 -> 256), identity residual ----
    k_f2b<<<2048, 256, 0, stream>>>(B3, hb, NN * 256);
    {
        dim3 g(MB, 2);
        k_gemm_mfma<128><<<g, 256, 0, stream>>>(hb, Wl1b, bl1, B0, NN, 256, 256);
        k_gemm_mfma<128><<<g, 256, 0, stream>>>(hb, Wr1b, br1, B1, NN, 256, 256);
    }
    k_gat_edge<256><<<EG, 256, 0, stream>>>(B0, B1, rp, csr_src, csr_ea,
                                            We1, att1, b1, g1, be1, B3, B2, NN);

    // ---- layer 2 (256 -> 1x64 mean = 64) ----
    k_f2b<<<2048, 256, 0, stream>>>(B2, hb, NN * 256);
    {
        dim3 g(MB, 1);
        k_gemm_mfma<64><<<g, 256, 0, stream>>>(hb, Wl2b, bl2, B0, NN, 64, 256);
        k_gemm_mfma<64><<<g, 256, 0, stream>>>(hb, Wr2b, br2, B1, NN, 64, 256);
        k_gemm_mfma<64><<<g, 256, 0, stream>>>(hb, Rw2b, Rb2, B3, NN, 64, 256);
    }
    k_gat_edge<64><<<EG, 256, 0, stream>>>(B0, B1, rp, csr_src, csr_ea,
                                           We2, att2, b2, g2, be2, B3, outp, NN);
}

// Round 4
// 895.955 us; speedup vs baseline: 2.0991x; 1.1861x over previous
//
#include <hip/hip_runtime.h>
#include <math.h>

static constexpr int NN = 50000;
static constexpr int NE = 800000;
static constexpr int MPAD = 50048;   // 391 * 128

typedef __attribute__((ext_vector_type(8))) __bf16 bf16x8;
typedef __attribute__((ext_vector_type(4))) __bf16 bf16x4;
typedef __attribute__((ext_vector_type(4))) float f32x4;
typedef __bf16 bf16_t;

__device__ __forceinline__ float leakyf(float x, float s) { return x > 0.f ? x : s * x; }

// ============================ CSR build ============================
__global__ void k_count(const int* __restrict__ dst, int* __restrict__ cnt, int n) {
    int e = blockIdx.x * 256 + threadIdx.x;
    if (e < n) atomicAdd(&cnt[dst[e]], 1);
}

__global__ void k_scan1(const int* __restrict__ cnt, int* __restrict__ rp,
                        int* __restrict__ partials, int n) {
    __shared__ int sm[256];
    int tid = threadIdx.x;
    int i = blockIdx.x * 256 + tid;
    int v = (i < n) ? cnt[i] : 0;
    int x = v;
    sm[tid] = x;
    __syncthreads();
    for (int off = 1; off < 256; off <<= 1) {
        int t = (tid >= off) ? sm[tid - off] : 0;
        __syncthreads();
        x += t;
        sm[tid] = x;
        __syncthreads();
    }
    if (i < n) rp[i] = x - v;
    if (tid == 255) partials[blockIdx.x] = x;
}

__global__ void k_scan2(const int* __restrict__ partials, int* __restrict__ poffs, int nb) {
    __shared__ int sm[256];
    int tid = threadIdx.x;
    int v = (tid < nb) ? partials[tid] : 0;
    int x = v;
    sm[tid] = x;
    __syncthreads();
    for (int off = 1; off < 256; off <<= 1) {
        int t = (tid >= off) ? sm[tid - off] : 0;
        __syncthreads();
        x += t;
        sm[tid] = x;
        __syncthreads();
    }
    if (tid < nb) poffs[tid] = x - v;
}

__global__ void k_scan3(int* __restrict__ rp, const int* __restrict__ poffs,
                        int* __restrict__ woff, int n, int total) {
    int i = blockIdx.x * 256 + threadIdx.x;
    if (i < n) {
        int v = rp[i] + poffs[blockIdx.x];
        rp[i] = v;
        woff[i] = v;
    }
    if (i == 0) rp[n] = total;
}

__global__ void k_scatter(const int* __restrict__ srcA, const int* __restrict__ dstA,
                          const float* __restrict__ ea, int* __restrict__ woff,
                          int* __restrict__ csr_src, float* __restrict__ csr_ea, int n) {
    int e = blockIdx.x * 256 + threadIdx.x;
    if (e < n) {
        int d = dstA[e];
        int pos = atomicAdd(&woff[d], 1);
        csr_src[pos] = srcA[e];
        csr_ea[pos] = ea[e];
    }
}

// ============================ f32 -> bf16 conversion ============================
__global__ void k_f2b(const float* __restrict__ s, bf16_t* __restrict__ d, int n) {
    for (int i = (blockIdx.x * 256 + threadIdx.x) * 8; i < n; i += gridDim.x * 256 * 8) {
        float4 a = *(const float4*)&s[i];
        float4 b = *(const float4*)&s[i + 4];
        bf16x8 o;
        o[0] = (__bf16)a.x; o[1] = (__bf16)a.y; o[2] = (__bf16)a.z; o[3] = (__bf16)a.w;
        o[4] = (__bf16)b.x; o[5] = (__bf16)b.y; o[6] = (__bf16)b.z; o[7] = (__bf16)b.w;
        *(bf16x8*)&d[i] = o;
    }
}

// 8 weight matrices in one launch (blockIdx.y selects matrix)
__global__ void k_f2bw(const float* s0, bf16_t* d0, int n0,
                       const float* s1, bf16_t* d1, int n1,
                       const float* s2, bf16_t* d2, int n2,
                       const float* s3, bf16_t* d3, int n3,
                       const float* s4, bf16_t* d4, int n4,
                       const float* s5, bf16_t* d5, int n5,
                       const float* s6, bf16_t* d6, int n6,
                       const float* s7, bf16_t* d7, int n7) {
    const float* s; bf16_t* d; int n;
    switch (blockIdx.y) {
        case 0: s = s0; d = d0; n = n0; break;
        case 1: s = s1; d = d1; n = n1; break;
        case 2: s = s2; d = d2; n = n2; break;
        case 3: s = s3; d = d3; n = n3; break;
        case 4: s = s4; d = d4; n = n4; break;
        case 5: s = s5; d = d5; n = n5; break;
        case 6: s = s6; d = d6; n = n6; break;
        default: s = s7; d = d7; n = n7; break;
    }
    for (int i = (blockIdx.x * 256 + threadIdx.x) * 8; i < n; i += gridDim.x * 256 * 8) {
        float4 a = *(const float4*)&s[i];
        float4 b = *(const float4*)&s[i + 4];
        bf16x8 o;
        o[0] = (__bf16)a.x; o[1] = (__bf16)a.y; o[2] = (__bf16)a.z; o[3] = (__bf16)a.w;
        o[4] = (__bf16)b.x; o[5] = (__bf16)b.y; o[6] = (__bf16)b.z; o[7] = (__bf16)b.w;
        *(bf16x8*)&d[i] = o;
    }
}

// concatenate 8 bias segments into the fused-bias pool (block per segment, n<=256)
__global__ void k_catb(float* __restrict__ dst,
                       const float* s0, int o0, int n0, const float* s1, int o1, int n1,
                       const float* s2, int o2, int n2, const float* s3, int o3, int n3,
                       const float* s4, int o4, int n4, const float* s5, int o5, int n5,
                       const float* s6, int o6, int n6, const float* s7, int o7, int n7) {
    const float* s; int off, n;
    switch (blockIdx.x) {
        case 0: s = s0; off = o0; n = n0; break;
        case 1: s = s1; off = o1; n = n1; break;
        case 2: s = s2; off = o2; n = n2; break;
        case 3: s = s3; off = o3; n = n3; break;
        case 4: s = s4; off = o4; n = n4; break;
        case 5: s = s5; off = o5; n = n5; break;
        case 6: s = s6; off = o6; n = n6; break;
        default: s = s7; off = o7; n = n7; break;
    }
    int i = threadIdx.x;
    if (i < n) dst[off + i] = s[i];
}

// ============================ MFMA GEMM (bf16 out) ============================
// C[Mpad,Nc]_bf16 = A[Mpad,K]_bf16 @ W[Nc,K]_bf16^T + bias. BM=128, BK=32.
// 4 waves in 2x2; wave tile 64 x (BN/2). K%32==0, Nc%BN==0, rows padded to 128.
template <int BN>
__global__ __launch_bounds__(256) void k_gemm_mfma(
    const bf16_t* __restrict__ A, const bf16_t* __restrict__ W,
    const float* __restrict__ bias, bf16_t* __restrict__ C,
    int Mpad, int Nc, int K) {
    constexpr int BM = 128;
    constexpr int FRN = BN / 32;       // B fragments per wave
    constexpr int WN = BN / 2;         // wave cols
    constexpr int BCHW = BN / 64;      // B staging chunks per wave

    __shared__ __align__(16) bf16_t As[BM * 32];
    __shared__ __align__(16) bf16_t Bs[BN * 32];

    const int tid = threadIdx.x;
    const int wid = tid >> 6;
    const int lane = tid & 63;
    const int wr = wid >> 1, wc = wid & 1;
    const int bm = blockIdx.x * BM;
    const int bn = blockIdx.y * BN;

    const int srow = lane >> 2;
    const int scol = (lane & 3) * 8;

    f32x4 acc[4][FRN];
#pragma unroll
    for (int m = 0; m < 4; ++m)
#pragma unroll
        for (int n = 0; n < FRN; ++n) acc[m][n] = (f32x4){0.f, 0.f, 0.f, 0.f};

    const bf16_t* ag[2];
#pragma unroll
    for (int j = 0; j < 2; ++j)
        ag[j] = A + (size_t)(bm + (wid * 2 + j) * 16 + srow) * K + scol;
    const bf16_t* bg[BCHW];
#pragma unroll
    for (int j = 0; j < BCHW; ++j)
        bg[j] = W + (size_t)(bn + (wid * BCHW + j) * 16 + srow) * K + scol;

    for (int k0 = 0; k0 < K; k0 += 32) {
#pragma unroll
        for (int j = 0; j < 2; ++j) {
            __builtin_amdgcn_global_load_lds(
                (const __attribute__((address_space(1))) void*)(ag[j] + k0),
                (__attribute__((address_space(3))) void*)(As + (wid * 2 + j) * 512),
                16, 0, 0);
        }
#pragma unroll
        for (int j = 0; j < BCHW; ++j) {
            __builtin_amdgcn_global_load_lds(
                (const __attribute__((address_space(1))) void*)(bg[j] + k0),
                (__attribute__((address_space(3))) void*)(Bs + (wid * BCHW + j) * 512),
                16, 0, 0);
        }
        __syncthreads();

        bf16x8 bfr[FRN];
#pragma unroll
        for (int n = 0; n < FRN; ++n)
            bfr[n] = *(const bf16x8*)&Bs[(wc * WN + n * 16 + (lane & 15)) * 32 + (lane >> 4) * 8];
        bf16x8 afr[4];
#pragma unroll
        for (int m = 0; m < 4; ++m)
            afr[m] = *(const bf16x8*)&As[(wr * 64 + m * 16 + (lane & 15)) * 32 + (lane >> 4) * 8];
#pragma unroll
        for (int m = 0; m < 4; ++m)
#pragma unroll
            for (int n = 0; n < FRN; ++n)
                acc[m][n] = __builtin_amdgcn_mfma_f32_16x16x32_bf16(afr[m], bfr[n], acc[m][n], 0, 0, 0);
        __syncthreads();
    }

    const int cr = (lane >> 4) * 4;
    const int cc = lane & 15;
#pragma unroll
    for (int m = 0; m < 4; ++m) {
        int row0 = bm + wr * 64 + m * 16 + cr;
#pragma unroll
        for (int n = 0; n < FRN; ++n) {
            int col = bn + wc * WN + n * 16 + cc;
            float bv = bias[col];
#pragma unroll
            for (int j = 0; j < 4; ++j) {
                C[(size_t)(row0 + j) * Nc + col] = (bf16_t)(acc[m][n][j] + bv);
            }
        }
    }
}

// ============================ Fused GAT edge + softmax + LN + residual ============================
// xl/xr are column-offset views into the fused GEMM output panel (stride fstride);
// res is a bf16 residual view (stride rstride). out has dense stride HC.
template <int HC, typename OutT>
__global__ __launch_bounds__(256) void k_gat_edge(
    const bf16_t* __restrict__ xl, const bf16_t* __restrict__ xr,
    const bf16_t* __restrict__ res, int fstride, int rstride,
    const int* __restrict__ rp, const int* __restrict__ csr_src,
    const float* __restrict__ csr_ea,
    const float* __restrict__ We, const float* __restrict__ att,
    const float* __restrict__ bias, const float* __restrict__ gamma,
    const float* __restrict__ beta,
    OutT* __restrict__ out, int n) {
    constexpr int VPL = HC / 64;
    constexpr int LPH = 64 * 64 / HC;     // lanes per head
    const int lane = threadIdx.x & 63;
    const int node = blockIdx.x * 4 + (threadIdx.x >> 6);
    if (node >= n) return;
    const int vb = lane * VPL;

    float xrd[VPL], wev[VPL], attv[VPL];
    if constexpr (VPL == 4) {
        bf16x4 t = *(const bf16x4*)&xr[(size_t)node * fstride + vb];
#pragma unroll
        for (int i = 0; i < 4; ++i) xrd[i] = (float)t[i];
    } else {
        xrd[0] = (float)xr[(size_t)node * fstride + vb];
    }
#pragma unroll
    for (int i = 0; i < VPL; ++i) {
        wev[i]  = We[vb + i];
        attv[i] = att[vb + i];
    }

    float m = -INFINITY, denom = 0.f;
    float acc[VPL] = {};
    const int s = rp[node], e = rp[node + 1];

    for (int p = s; p < e; ++p) {
        int src  = csr_src[p];
        float ea = csr_ea[p];
        float xls[VPL];
        if constexpr (VPL == 4) {
            bf16x4 t = *(const bf16x4*)&xl[(size_t)src * fstride + vb];
#pragma unroll
            for (int i = 0; i < 4; ++i) xls[i] = (float)t[i];
        } else {
            xls[0] = (float)xl[(size_t)src * fstride + vb];
        }
        float part = 0.f;
#pragma unroll
        for (int i = 0; i < VPL; ++i) {
            float z = xls[i] + xrd[i] + ea * wev[i];
            z = leakyf(z, 0.2f);
            part += attv[i] * z;
        }
#pragma unroll
        for (int off = 1; off < LPH; off <<= 1) part += __shfl_xor(part, off);
        float mn = fmaxf(m, part);
        float sc = __expf(m - mn);
        float pw = __expf(part - mn);
        denom = denom * sc + pw;
#pragma unroll
        for (int i = 0; i < VPL; ++i) acc[i] = acc[i] * sc + pw * xls[i];
        m = mn;
    }

    float o[VPL];
    float inv = (e > s) ? 1.f / denom : 0.f;
#pragma unroll
    for (int i = 0; i < VPL; ++i) o[i] = acc[i] * inv + bias[vb + i];

    float sum = 0.f;
#pragma unroll
    for (int i = 0; i < VPL; ++i) sum += o[i];
#pragma unroll
    for (int off = 1; off < 64; off <<= 1) sum += __shfl_xor(sum, off);
    float mu = sum * (1.f / HC);
    float sq = 0.f;
#pragma unroll
    for (int i = 0; i < VPL; ++i) { float d = o[i] - mu; sq += d * d; }
#pragma unroll
    for (int off = 1; off < 64; off <<= 1) sq += __shfl_xor(sq, off);
    float rstd = rsqrtf(sq * (1.f / HC) + 1e-5f);

    float rv[VPL];
    if constexpr (VPL == 4) {
        bf16x4 t = *(const bf16x4*)&res[(size_t)node * rstride + vb];
#pragma unroll
        for (int i = 0; i < 4; ++i) rv[i] = (float)t[i];
    } else {
        rv[0] = (float)res[(size_t)node * rstride + vb];
    }

#pragma unroll
    for (int i = 0; i < VPL; ++i) {
        float y = (o[i] - mu) * rstd * gamma[vb + i] + beta[vb + i];
        y = leakyf(y, 0.01f);
        out[(size_t)node * HC + vb + i] = (OutT)(y + rv[i]);
    }
}

// ============================ launch ============================
extern "C" void kernel_launch(void* const* d_in, const int* in_sizes, int n_in,
                              void* d_out, int out_size, void* d_ws, size_t ws_size,
                              hipStream_t stream) {
    const int*   ei  = (const int*)d_in[0];
    const float* ea  = (const float*)d_in[1];
    const float* x   = (const float*)d_in[2];
    const float* Wl0 = (const float*)d_in[3],  *bl0 = (const float*)d_in[4];
    const float* Wr0 = (const float*)d_in[5],  *br0 = (const float*)d_in[6];
    const float* We0 = (const float*)d_in[7],  *att0= (const float*)d_in[8];
    const float* b0  = (const float*)d_in[9],  *g0  = (const float*)d_in[10], *be0 = (const float*)d_in[11];
    const float* Wl1 = (const float*)d_in[12], *bl1 = (const float*)d_in[13];
    const float* Wr1 = (const float*)d_in[14], *br1 = (const float*)d_in[15];
    const float* We1 = (const float*)d_in[16], *att1= (const float*)d_in[17];
    const float* b1  = (const float*)d_in[18], *g1  = (const float*)d_in[19], *be1 = (const float*)d_in[20];
    const float* Wl2 = (const float*)d_in[21], *bl2 = (const float*)d_in[22];
    const float* Wr2 = (const float*)d_in[23], *br2 = (const float*)d_in[24];
    const float* We2 = (const float*)d_in[25], *att2= (const float*)d_in[26];
    const float* b2  = (const float*)d_in[27], *g2  = (const float*)d_in[28], *be2 = (const float*)d_in[29];
    const float* Rw0 = (const float*)d_in[30], *Rb0 = (const float*)d_in[31];
    const float* Rw2 = (const float*)d_in[32], *Rb2 = (const float*)d_in[33];

    const int* srcA = ei;
    const int* dstA = ei + NE;

    float* ws = (float*)d_ws;
    size_t o = 0;
    auto allocf = [&](size_t nf) { float* p = ws + o; o += nf; return p; };
    bf16_t* xb  = (bf16_t*)allocf((size_t)MPAD * 384);   // bf16 x       [MPAD,768]
    bf16_t* C0  = (bf16_t*)allocf((size_t)MPAD * 384);   // layer0 panel [MPAD,768] xl|xr|res
    bf16_t* C1  = (bf16_t*)allocf((size_t)MPAD * 256);   // layer1 panel [MPAD,512] xl|xr
    bf16_t* C2  = (bf16_t*)allocf((size_t)MPAD * 96);    // layer2 panel [MPAD,192] xl|xr|res
    bf16_t* h0b = (bf16_t*)allocf((size_t)MPAD * 128);   // h  bf16      [MPAD,256]
    bf16_t* h1b = (bf16_t*)allocf((size_t)MPAD * 128);   // h1 bf16      [MPAD,256]
    bf16_t* wb  = (bf16_t*)allocf(786432 / 2);           // bf16 weights (770048 used)
    float* bcat = allocf(1536);                          // fused biases: 768|512|192
    int* cnt      = (int*)(ws + o); o += NN;
    int* rp       = (int*)(ws + o); o += NN + 4;
    int* woff     = (int*)(ws + o); o += NN;
    int* partials = (int*)(ws + o); o += 256;
    int* poffs    = (int*)(ws + o); o += 256;
    int* csr_src  = (int*)(ws + o); o += NE;
    float* csr_ea = (float*)(ws + o); o += NE;

    bf16_t* Wl0b = wb;                   // [256,768] x3 stacked -> [768,768]
    bf16_t* Wr0b = Wl0b + 196608;
    bf16_t* Rw0b = Wr0b + 196608;
    bf16_t* Wl1b = Rw0b + 196608;        // [256,256] x2 stacked -> [512,256]
    bf16_t* Wr1b = Wl1b + 65536;
    bf16_t* Wl2b = Wr1b + 65536;         // [64,256] x3 stacked -> [192,256]
    bf16_t* Wr2b = Wl2b + 16384;
    bf16_t* Rw2b = Wr2b + 16384;

    float* outp = (float*)d_out;

    const int NB_N = (NN + 255) / 256;
    const int NB_E = (NE + 255) / 256;

    // ---- CSR build ----
    hipMemsetAsync(cnt, 0, (size_t)NN * sizeof(int), stream);
    k_count<<<NB_E, 256, 0, stream>>>(dstA, cnt, NE);
    k_scan1<<<NB_N, 256, 0, stream>>>(cnt, rp, partials, NN);
    k_scan2<<<1, 256, 0, stream>>>(partials, poffs, NB_N);
    k_scan3<<<NB_N, 256, 0, stream>>>(rp, poffs, woff, NN, NE);
    k_scatter<<<NB_E, 256, 0, stream>>>(srcA, dstA, ea, woff, csr_src, csr_ea, NE);

    // ---- dtype conversions (x + all weights) + fused bias pool ----
    k_f2b<<<2048, 256, 0, stream>>>(x, xb, NN * 768);
    {
        dim3 g(96, 8);
        k_f2bw<<<g, 256, 0, stream>>>(Wl0, Wl0b, 196608, Wr0, Wr0b, 196608,
                                      Rw0, Rw0b, 196608, Wl1, Wl1b, 65536,
                                      Wr1, Wr1b, 65536,  Wl2, Wl2b, 16384,
                                      Wr2, Wr2b, 16384,  Rw2, Rw2b, 16384);
    }
    k_catb<<<8, 256, 0, stream>>>(bcat,
                                  bl0, 0, 256,    br0, 256, 256,  Rb0, 512, 256,
                                  bl1, 768, 256,  br1, 1024, 256,
                                  bl2, 1280, 64,  br2, 1344, 64,  Rb2, 1408, 64);

    const int MB = MPAD / 128;            // 391
    const int EG = (NN + 3) / 4;

    // ---- layer 0: fused GEMM [xl|xr|res] = x @ [Wl0;Wr0;Rw0]^T ----
    {
        dim3 g(MB, 6);
        k_gemm_mfma<128><<<g, 256, 0, stream>>>(xb, Wl0b, bcat, C0, MPAD, 768, 768);
    }
    k_gat_edge<256, bf16_t><<<EG, 256, 0, stream>>>(
        C0, C0 + 256, C0 + 512, 768, 768, rp, csr_src, csr_ea,
        We0, att0, b0, g0, be0, h0b, NN);

    // ---- layer 1: fused GEMM [xl|xr] = h @ [Wl1;Wr1]^T, identity residual ----
    {
        dim3 g(MB, 4);
        k_gemm_mfma<128><<<g, 256, 0, stream>>>(h0b, Wl1b, bcat + 768, C1, MPAD, 512, 256);
    }
    k_gat_edge<256, bf16_t><<<EG, 256, 0, stream>>>(
        C1, C1 + 256, h0b, 512, 256, rp, csr_src, csr_ea,
        We1, att1, b1, g1, be1, h1b, NN);

    // ---- layer 2: fused GEMM [xl|xr|res] = h1 @ [Wl2;Wr2;Rw2]^T ----
    {
        dim3 g(MB, 3);
        k_gemm_mfma<64><<<g, 256, 0, stream>>>(h1b, Wl2b, bcat + 1280, C2, MPAD, 192, 256);
    }
    k_gat_edge<64, float><<<EG, 256, 0, stream>>>(
        C2, C2 + 64, C2 + 128, 192, 192, rp, csr_src, csr_ea,
        We2, att2, b2, g2, be2, outp, NN);
}

// Round 5
// 781.596 us; speedup vs baseline: 2.4062x; 1.1463x over previous
//
#include <hip/hip_runtime.h>
#include <math.h>

static constexpr int NN = 50000;
static constexpr int NE = 800000;
static constexpr int MPAD = 50048;   // 391 * 128

typedef __attribute__((ext_vector_type(8))) __bf16 bf16x8;
typedef __attribute__((ext_vector_type(4))) __bf16 bf16x4;
typedef __attribute__((ext_vector_type(4))) float f32x4;
typedef __bf16 bf16_t;

__device__ __forceinline__ float leakyf(float x, float s) { return fmaxf(x, s * x); }

// ============================ CSR build ============================
__global__ void k_count(const int* __restrict__ dst, int* __restrict__ cnt, int n) {
    int e = blockIdx.x * 256 + threadIdx.x;
    if (e < n) atomicAdd(&cnt[dst[e]], 1);
}

__global__ void k_scan1(const int* __restrict__ cnt, int* __restrict__ rp,
                        int* __restrict__ partials, int n) {
    __shared__ int sm[256];
    int tid = threadIdx.x;
    int i = blockIdx.x * 256 + tid;
    int v = (i < n) ? cnt[i] : 0;
    int x = v;
    sm[tid] = x;
    __syncthreads();
    for (int off = 1; off < 256; off <<= 1) {
        int t = (tid >= off) ? sm[tid - off] : 0;
        __syncthreads();
        x += t;
        sm[tid] = x;
        __syncthreads();
    }
    if (i < n) rp[i] = x - v;
    if (tid == 255) partials[blockIdx.x] = x;
}

__global__ void k_scan2(const int* __restrict__ partials, int* __restrict__ poffs, int nb) {
    __shared__ int sm[256];
    int tid = threadIdx.x;
    int v = (tid < nb) ? partials[tid] : 0;
    int x = v;
    sm[tid] = x;
    __syncthreads();
    for (int off = 1; off < 256; off <<= 1) {
        int t = (tid >= off) ? sm[tid - off] : 0;
        __syncthreads();
        x += t;
        sm[tid] = x;
        __syncthreads();
    }
    if (tid < nb) poffs[tid] = x - v;
}

__global__ void k_scan3(int* __restrict__ rp, const int* __restrict__ poffs,
                        int* __restrict__ woff, int n, int total) {
    int i = blockIdx.x * 256 + threadIdx.x;
    if (i < n) {
        int v = rp[i] + poffs[blockIdx.x];
        rp[i] = v;
        woff[i] = v;
    }
    if (i == 0) rp[n] = total;
}

__global__ void k_scatter(const int* __restrict__ srcA, const int* __restrict__ dstA,
                          const float* __restrict__ ea, int* __restrict__ woff,
                          int* __restrict__ csr_src, float* __restrict__ csr_ea, int n) {
    int e = blockIdx.x * 256 + threadIdx.x;
    if (e < n) {
        int d = dstA[e];
        int pos = atomicAdd(&woff[d], 1);
        csr_src[pos] = srcA[e];
        csr_ea[pos] = ea[e];
    }
}

// ============================ f32 -> bf16 conversion ============================
__global__ void k_f2b(const float* __restrict__ s, bf16_t* __restrict__ d, int n) {
    for (int i = (blockIdx.x * 256 + threadIdx.x) * 8; i < n; i += gridDim.x * 256 * 8) {
        float4 a = *(const float4*)&s[i];
        float4 b = *(const float4*)&s[i + 4];
        bf16x8 o;
        o[0] = (__bf16)a.x; o[1] = (__bf16)a.y; o[2] = (__bf16)a.z; o[3] = (__bf16)a.w;
        o[4] = (__bf16)b.x; o[5] = (__bf16)b.y; o[6] = (__bf16)b.z; o[7] = (__bf16)b.w;
        *(bf16x8*)&d[i] = o;
    }
}

// 8 weight matrices in one launch (blockIdx.y selects matrix)
__global__ void k_f2bw(const float* s0, bf16_t* d0, int n0,
                       const float* s1, bf16_t* d1, int n1,
                       const float* s2, bf16_t* d2, int n2,
                       const float* s3, bf16_t* d3, int n3,
                       const float* s4, bf16_t* d4, int n4,
                       const float* s5, bf16_t* d5, int n5,
                       const float* s6, bf16_t* d6, int n6,
                       const float* s7, bf16_t* d7, int n7) {
    const float* s; bf16_t* d; int n;
    switch (blockIdx.y) {
        case 0: s = s0; d = d0; n = n0; break;
        case 1: s = s1; d = d1; n = n1; break;
        case 2: s = s2; d = d2; n = n2; break;
        case 3: s = s3; d = d3; n = n3; break;
        case 4: s = s4; d = d4; n = n4; break;
        case 5: s = s5; d = d5; n = n5; break;
        case 6: s = s6; d = d6; n = n6; break;
        default: s = s7; d = d7; n = n7; break;
    }
    for (int i = (blockIdx.x * 256 + threadIdx.x) * 8; i < n; i += gridDim.x * 256 * 8) {
        float4 a = *(const float4*)&s[i];
        float4 b = *(const float4*)&s[i + 4];
        bf16x8 o;
        o[0] = (__bf16)a.x; o[1] = (__bf16)a.y; o[2] = (__bf16)a.z; o[3] = (__bf16)a.w;
        o[4] = (__bf16)b.x; o[5] = (__bf16)b.y; o[6] = (__bf16)b.z; o[7] = (__bf16)b.w;
        *(bf16x8*)&d[i] = o;
    }
}

// concatenate 8 bias segments into the fused-bias pool (block per segment, n<=256)
__global__ void k_catb(float* __restrict__ dst,
                       const float* s0, int o0, int n0, const float* s1, int o1, int n1,
                       const float* s2, int o2, int n2, const float* s3, int o3, int n3,
                       const float* s4, int o4, int n4, const float* s5, int o5, int n5,
                       const float* s6, int o6, int n6, const float* s7, int o7, int n7) {
    const float* s; int off, n;
    switch (blockIdx.x) {
        case 0: s = s0; off = o0; n = n0; break;
        case 1: s = s1; off = o1; n = n1; break;
        case 2: s = s2; off = o2; n = n2; break;
        case 3: s = s3; off = o3; n = n3; break;
        case 4: s = s4; off = o4; n = n4; break;
        case 5: s = s5; off = o5; n = n5; break;
        case 6: s = s6; off = o6; n = n6; break;
        default: s = s7; off = o7; n = n7; break;
    }
    int i = threadIdx.x;
    if (i < n) dst[off + i] = s[i];
}

// ============================ MFMA GEMM (bf16 out) ============================
// C[Mpad,Nc]_bf16 = A[Mpad,K]_bf16 @ W[Nc,K]_bf16^T + bias. BM=128, BK=32.
template <int BN>
__global__ __launch_bounds__(256) void k_gemm_mfma(
    const bf16_t* __restrict__ A, const bf16_t* __restrict__ W,
    const float* __restrict__ bias, bf16_t* __restrict__ C,
    int Mpad, int Nc, int K) {
    constexpr int BM = 128;
    constexpr int FRN = BN / 32;
    constexpr int WN = BN / 2;
    constexpr int BCHW = BN / 64;

    __shared__ __align__(16) bf16_t As[BM * 32];
    __shared__ __align__(16) bf16_t Bs[BN * 32];

    const int tid = threadIdx.x;
    const int wid = tid >> 6;
    const int lane = tid & 63;
    const int wr = wid >> 1, wc = wid & 1;
    const int bm = blockIdx.x * BM;
    const int bn = blockIdx.y * BN;

    const int srow = lane >> 2;
    const int scol = (lane & 3) * 8;

    f32x4 acc[4][FRN];
#pragma unroll
    for (int m = 0; m < 4; ++m)
#pragma unroll
        for (int n = 0; n < FRN; ++n) acc[m][n] = (f32x4){0.f, 0.f, 0.f, 0.f};

    const bf16_t* ag[2];
#pragma unroll
    for (int j = 0; j < 2; ++j)
        ag[j] = A + (size_t)(bm + (wid * 2 + j) * 16 + srow) * K + scol;
    const bf16_t* bg[BCHW];
#pragma unroll
    for (int j = 0; j < BCHW; ++j)
        bg[j] = W + (size_t)(bn + (wid * BCHW + j) * 16 + srow) * K + scol;

    for (int k0 = 0; k0 < K; k0 += 32) {
#pragma unroll
        for (int j = 0; j < 2; ++j) {
            __builtin_amdgcn_global_load_lds(
                (const __attribute__((address_space(1))) void*)(ag[j] + k0),
                (__attribute__((address_space(3))) void*)(As + (wid * 2 + j) * 512),
                16, 0, 0);
        }
#pragma unroll
        for (int j = 0; j < BCHW; ++j) {
            __builtin_amdgcn_global_load_lds(
                (const __attribute__((address_space(1))) void*)(bg[j] + k0),
                (__attribute__((address_space(3))) void*)(Bs + (wid * BCHW + j) * 512),
                16, 0, 0);
        }
        __syncthreads();

        bf16x8 bfr[FRN];
#pragma unroll
        for (int n = 0; n < FRN; ++n)
            bfr[n] = *(const bf16x8*)&Bs[(wc * WN + n * 16 + (lane & 15)) * 32 + (lane >> 4) * 8];
        bf16x8 afr[4];
#pragma unroll
        for (int m = 0; m < 4; ++m)
            afr[m] = *(const bf16x8*)&As[(wr * 64 + m * 16 + (lane & 15)) * 32 + (lane >> 4) * 8];
#pragma unroll
        for (int m = 0; m < 4; ++m)
#pragma unroll
            for (int n = 0; n < FRN; ++n)
                acc[m][n] = __builtin_amdgcn_mfma_f32_16x16x32_bf16(afr[m], bfr[n], acc[m][n], 0, 0, 0);
        __syncthreads();
    }

    const int cr = (lane >> 4) * 4;
    const int cc = lane & 15;
#pragma unroll
    for (int m = 0; m < 4; ++m) {
        int row0 = bm + wr * 64 + m * 16 + cr;
#pragma unroll
        for (int n = 0; n < FRN; ++n) {
            int col = bn + wc * WN + n * 16 + cc;
            float bv = bias[col];
#pragma unroll
            for (int j = 0; j < 4; ++j) {
                C[(size_t)(row0 + j) * Nc + col] = (bf16_t)(acc[m][n][j] + bv);
            }
        }
    }
}

// ============================ Fused GAT edge + softmax + LN + residual ============================
// Max-free softmax (shift-invariant; logits clamped to +-60 as overflow insurance).
// ES edge slots per wave; each slot = CL lanes covering all HC channels (VPL per lane).
// att is prescaled by log2(e) so pw = exp2(part) = exp(att.z).
template <int HC, int ES, typename OutT>
__global__ __launch_bounds__(256) void k_gat_edge(
    const bf16_t* __restrict__ xl, const bf16_t* __restrict__ xr,
    const bf16_t* __restrict__ res, int fstride, int rstride,
    const int* __restrict__ rp, const int* __restrict__ csr_src,
    const float* __restrict__ csr_ea,
    const float* __restrict__ We, const float* __restrict__ att,
    const float* __restrict__ bias, const float* __restrict__ gamma,
    const float* __restrict__ beta,
    OutT* __restrict__ out, int n) {
    constexpr int CL  = 64 / ES;          // channel lanes per slot
    constexpr int VPL = HC / CL;          // channels per lane (4 or 8)
    constexpr int RW  = 64 / VPL;         // lanes per head (head = 64 ch); RW <= CL
    const int lane = threadIdx.x & 63;
    const int node = blockIdx.x * 4 + (threadIdx.x >> 6);
    if (node >= n) return;
    const int slot = lane / CL;
    const int cl   = lane % CL;
    const int vb   = cl * VPL;

    float xrd[VPL], wev[VPL], attv[VPL];
    if constexpr (VPL == 8) {
        bf16x8 t = *(const bf16x8*)&xr[(size_t)node * fstride + vb];
#pragma unroll
        for (int i = 0; i < 8; ++i) xrd[i] = (float)t[i];
    } else {
        bf16x4 t = *(const bf16x4*)&xr[(size_t)node * fstride + vb];
#pragma unroll
        for (int i = 0; i < 4; ++i) xrd[i] = (float)t[i];
    }
#pragma unroll
    for (int i = 0; i < VPL; ++i) {
        wev[i]  = We[vb + i];
        attv[i] = att[vb + i] * 1.44269504088896f;   // log2(e)
    }

    float denom = 0.f;
    float acc[VPL] = {};
    const int s = rp[node], e = rp[node + 1];

    for (int p0 = s; p0 < e; p0 += ES) {
        const int p = p0 + slot;
        const bool act = (p < e);
        const int pc = act ? p : (e - 1);
        const int src = csr_src[pc];
        const float ea = csr_ea[pc];
        float xls[VPL];
        if constexpr (VPL == 8) {
            bf16x8 t = *(const bf16x8*)&xl[(size_t)src * fstride + vb];
#pragma unroll
            for (int i = 0; i < 8; ++i) xls[i] = (float)t[i];
        } else {
            bf16x4 t = *(const bf16x4*)&xl[(size_t)src * fstride + vb];
#pragma unroll
            for (int i = 0; i < 4; ++i) xls[i] = (float)t[i];
        }
        float part = 0.f;
#pragma unroll
        for (int i = 0; i < VPL; ++i) {
            float z = fmaf(ea, wev[i], xls[i] + xrd[i]);
            z = leakyf(z, 0.2f);
            part = fmaf(attv[i], z, part);
        }
#pragma unroll
        for (int off = 1; off < RW; off <<= 1) part += __shfl_xor(part, off);
        part = fminf(fmaxf(part, -60.f), 60.f);
        const float pw = act ? exp2f(part) : 0.f;
        denom += pw;
#pragma unroll
        for (int i = 0; i < VPL; ++i) acc[i] = fmaf(pw, xls[i], acc[i]);
    }

    // cross-slot reduction (sums the ES partial aggregates of this node)
#pragma unroll
    for (int off = CL; off < 64; off <<= 1) {
        denom += __shfl_xor(denom, off);
#pragma unroll
        for (int i = 0; i < VPL; ++i) acc[i] += __shfl_xor(acc[i], off);
    }

    float o[VPL];
    const float inv = (e > s) ? 1.f / denom : 0.f;
#pragma unroll
    for (int i = 0; i < VPL; ++i) o[i] = fmaf(acc[i], inv, bias[vb + i]);

    // LayerNorm over HC channels (reduction within the CL-lane slot group)
    float sum = 0.f;
#pragma unroll
    for (int i = 0; i < VPL; ++i) sum += o[i];
#pragma unroll
    for (int off = 1; off < CL; off <<= 1) sum += __shfl_xor(sum, off);
    const float mu = sum * (1.f / HC);
    float sq = 0.f;
#pragma unroll
    for (int i = 0; i < VPL; ++i) { float d = o[i] - mu; sq += d * d; }
#pragma unroll
    for (int off = 1; off < CL; off <<= 1) sq += __shfl_xor(sq, off);
    const float rstd = rsqrtf(sq * (1.f / HC) + 1e-5f);

    float rv[VPL];
    if constexpr (VPL == 8) {
        bf16x8 t = *(const bf16x8*)&res[(size_t)node * rstride + vb];
#pragma unroll
        for (int i = 0; i < 8; ++i) rv[i] = (float)t[i];
    } else {
        bf16x4 t = *(const bf16x4*)&res[(size_t)node * rstride + vb];
#pragma unroll
        for (int i = 0; i < 4; ++i) rv[i] = (float)t[i];
    }

    if (slot == 0) {
#pragma unroll
        for (int i = 0; i < VPL; ++i) {
            float y = (o[i] - mu) * rstd * gamma[vb + i] + beta[vb + i];
            y = leakyf(y, 0.01f);
            out[(size_t)node * HC + vb + i] = (OutT)(y + rv[i]);
        }
    }
}

// ============================ launch ============================
extern "C" void kernel_launch(void* const* d_in, const int* in_sizes, int n_in,
                              void* d_out, int out_size, void* d_ws, size_t ws_size,
                              hipStream_t stream) {
    const int*   ei  = (const int*)d_in[0];
    const float* ea  = (const float*)d_in[1];
    const float* x   = (const float*)d_in[2];
    const float* Wl0 = (const float*)d_in[3],  *bl0 = (const float*)d_in[4];
    const float* Wr0 = (const float*)d_in[5],  *br0 = (const float*)d_in[6];
    const float* We0 = (const float*)d_in[7],  *att0= (const float*)d_in[8];
    const float* b0  = (const float*)d_in[9],  *g0  = (const float*)d_in[10], *be0 = (const float*)d_in[11];
    const float* Wl1 = (const float*)d_in[12], *bl1 = (const float*)d_in[13];
    const float* Wr1 = (const float*)d_in[14], *br1 = (const float*)d_in[15];
    const float* We1 = (const float*)d_in[16], *att1= (const float*)d_in[17];
    const float* b1  = (const float*)d_in[18], *g1  = (const float*)d_in[19], *be1 = (const float*)d_in[20];
    const float* Wl2 = (const float*)d_in[21], *bl2 = (const float*)d_in[22];
    const float* Wr2 = (const float*)d_in[23], *br2 = (const float*)d_in[24];
    const float* We2 = (const float*)d_in[25], *att2= (const float*)d_in[26];
    const float* b2  = (const float*)d_in[27], *g2  = (const float*)d_in[28], *be2 = (const float*)d_in[29];
    const float* Rw0 = (const float*)d_in[30], *Rb0 = (const float*)d_in[31];
    const float* Rw2 = (const float*)d_in[32], *Rb2 = (const float*)d_in[33];

    const int* srcA = ei;
    const int* dstA = ei + NE;

    float* ws = (float*)d_ws;
    size_t o = 0;
    auto allocf = [&](size_t nf) { float* p = ws + o; o += nf; return p; };
    bf16_t* xb  = (bf16_t*)allocf((size_t)MPAD * 384);   // bf16 x       [MPAD,768]
    bf16_t* C0  = (bf16_t*)allocf((size_t)MPAD * 384);   // layer0 panel [MPAD,768] xl|xr|res
    bf16_t* C1  = (bf16_t*)allocf((size_t)MPAD * 256);   // layer1 panel [MPAD,512] xl|xr
    bf16_t* C2  = (bf16_t*)allocf((size_t)MPAD * 96);    // layer2 panel [MPAD,192] xl|xr|res
    bf16_t* h0b = (bf16_t*)allocf((size_t)MPAD * 128);   // h  bf16      [MPAD,256]
    bf16_t* h1b = (bf16_t*)allocf((size_t)MPAD * 128);   // h1 bf16      [MPAD,256]
    bf16_t* wb  = (bf16_t*)allocf(786432 / 2);           // bf16 weights (770048 used)
    float* bcat = allocf(1536);                          // fused biases: 768|512|192
    int* cnt      = (int*)(ws + o); o += NN;
    int* rp       = (int*)(ws + o); o += NN + 4;
    int* woff     = (int*)(ws + o); o += NN;
    int* partials = (int*)(ws + o); o += 256;
    int* poffs    = (int*)(ws + o); o += 256;
    int* csr_src  = (int*)(ws + o); o += NE;
    float* csr_ea = (float*)(ws + o); o += NE;

    bf16_t* Wl0b = wb;                   // [256,768] x3 stacked -> [768,768]
    bf16_t* Wr0b = Wl0b + 196608;
    bf16_t* Rw0b = Wr0b + 196608;
    bf16_t* Wl1b = Rw0b + 196608;        // [256,256] x2 stacked -> [512,256]
    bf16_t* Wr1b = Wl1b + 65536;
    bf16_t* Wl2b = Wr1b + 65536;         // [64,256] x3 stacked -> [192,256]
    bf16_t* Wr2b = Wl2b + 16384;
    bf16_t* Rw2b = Wr2b + 16384;

    float* outp = (float*)d_out;

    const int NB_N = (NN + 255) / 256;
    const int NB_E = (NE + 255) / 256;

    // ---- CSR build ----
    hipMemsetAsync(cnt, 0, (size_t)NN * sizeof(int), stream);
    k_count<<<NB_E, 256, 0, stream>>>(dstA, cnt, NE);
    k_scan1<<<NB_N, 256, 0, stream>>>(cnt, rp, partials, NN);
    k_scan2<<<1, 256, 0, stream>>>(partials, poffs, NB_N);
    k_scan3<<<NB_N, 256, 0, stream>>>(rp, poffs, woff, NN, NE);
    k_scatter<<<NB_E, 256, 0, stream>>>(srcA, dstA, ea, woff, csr_src, csr_ea, NE);

    // ---- dtype conversions (x + all weights) + fused bias pool ----
    k_f2b<<<2048, 256, 0, stream>>>(x, xb, NN * 768);
    {
        dim3 g(96, 8);
        k_f2bw<<<g, 256, 0, stream>>>(Wl0, Wl0b, 196608, Wr0, Wr0b, 196608,
                                      Rw0, Rw0b, 196608, Wl1, Wl1b, 65536,
                                      Wr1, Wr1b, 65536,  Wl2, Wl2b, 16384,
                                      Wr2, Wr2b, 16384,  Rw2, Rw2b, 16384);
    }
    k_catb<<<8, 256, 0, stream>>>(bcat,
                                  bl0, 0, 256,    br0, 256, 256,  Rb0, 512, 256,
                                  bl1, 768, 256,  br1, 1024, 256,
                                  bl2, 1280, 64,  br2, 1344, 64,  Rb2, 1408, 64);

    const int MB = MPAD / 128;            // 391
    const int EG = (NN + 3) / 4;

    // ---- layer 0: fused GEMM [xl|xr|res] = x @ [Wl0;Wr0;Rw0]^T ----
    {
        dim3 g(MB, 6);
        k_gemm_mfma<128><<<g, 256, 0, stream>>>(xb, Wl0b, bcat, C0, MPAD, 768, 768);
    }
    k_gat_edge<256, 2, bf16_t><<<EG, 256, 0, stream>>>(
        C0, C0 + 256, C0 + 512, 768, 768, rp, csr_src, csr_ea,
        We0, att0, b0, g0, be0, h0b, NN);

    // ---- layer 1: fused GEMM [xl|xr] = h @ [Wl1;Wr1]^T, identity residual ----
    {
        dim3 g(MB, 4);
        k_gemm_mfma<128><<<g, 256, 0, stream>>>(h0b, Wl1b, bcat + 768, C1, MPAD, 512, 256);
    }
    k_gat_edge<256, 2, bf16_t><<<EG, 256, 0, stream>>>(
        C1, C1 + 256, h0b, 512, 256, rp, csr_src, csr_ea,
        We1, att1, b1, g1, be1, h1b, NN);

    // ---- layer 2: fused GEMM [xl|xr|res] = h1 @ [Wl2;Wr2;Rw2]^T ----
    {
        dim3 g(MB, 3);
        k_gemm_mfma<64><<<g, 256, 0, stream>>>(h1b, Wl2b, bcat + 1280, C2, MPAD, 192, 256);
    }
    k_gat_edge<64, 4, float><<<EG, 256, 0, stream>>>(
        C2, C2 + 64, C2 + 128, 192, 192, rp, csr_src, csr_ea,
        We2, att2, b2, g2, be2, outp, NN);
}